// Round 3
// baseline (444.890 us; speedup 1.0000x reference)
//
#include <hip/hip_runtime.h>
#include <math.h>

#define B 128
#define M 32
#define P 8732
#define C 21
#define THRESH 0.5f
#define ALPHA 10.0f
#define TPB2 256        // k2 threads per block == priors per block
#define NB2 35          // ceil(P/TPB2)

// ---------------- k1: best prior per object (obj_idx) -----------------------
__global__ __launch_bounds__(256) void k1_objargmax(
    const float* __restrict__ b_boxes, const float* __restrict__ priors,
    int* __restrict__ objidx) {
  int wid = threadIdx.x >> 6;
  int lane = threadIdx.x & 63;
  int task = blockIdx.x * 4 + wid;  // (b*M + m)
  if (task >= B * M) return;
  const float* bx = b_boxes + (size_t)task * 4;
  float x1 = bx[0], y1 = bx[1], x2 = bx[2], y2 = bx[3];
  float areaA = (x2 - x1) * (y2 - y1);
  float best = -1.0f;
  int bi = P;
  for (int p = lane; p < P; p += 64) {
    float4 pr = ((const float4*)priors)[p];
    float pw2 = pr.z * 0.5f, ph2 = pr.w * 0.5f;
    float iw = fminf(x2, pr.x + pw2) - fmaxf(x1, pr.x - pw2);
    float ih = fminf(y2, pr.y + ph2) - fmaxf(y1, pr.y - ph2);
    iw = fmaxf(iw, 0.0f);
    ih = fmaxf(ih, 0.0f);
    float inter = iw * ih;
    float iou = inter / (areaA + pr.z * pr.w - inter);
    if (iou > best) { best = iou; bi = p; }  // strict > keeps smallest p
  }
  for (int off = 32; off >= 1; off >>= 1) {
    float ov = __shfl_xor(best, off, 64);
    int oi = __shfl_xor(bi, off, 64);
    if (ov > best || (ov == best && oi < bi)) { best = ov; bi = oi; }
  }
  if (lane == 0) objidx[task] = bi;
}

// ---------------- k2: per-prior match + loc partial + CE --------------------
// NO global atomics: per-block partials plain-stored to ws.
__global__ __launch_bounds__(TPB2) void k2_perprior(
    const float* __restrict__ pred_loc, const float* __restrict__ pred_cls,
    const float* __restrict__ b_boxes, const int* __restrict__ b_labels,
    const float* __restrict__ priors, const int* __restrict__ objidx,
    float* __restrict__ ploc, float* __restrict__ pce, int* __restrict__ pnp,
    float* __restrict__ confneg) {
  int b = blockIdx.y;
  int p0 = blockIdx.x * TPB2;
  int nact = P - p0;
  if (nact > TPB2) nact = TPB2;
  int tid = threadIdx.x;

  __shared__ float sCls[TPB2 * C];  // 21504 B
  __shared__ float sx1[M], sy1[M], sx2[M], sy2[M], sarea[M];
  __shared__ int slab[M], sobj[M];

  if (tid < M) {
    int m = tid;
    float4 bx = ((const float4*)b_boxes)[b * M + m];
    sx1[m] = bx.x; sy1[m] = bx.y; sx2[m] = bx.z; sy2[m] = bx.w;
    sarea[m] = (bx.z - bx.x) * (bx.w - bx.y);
    slab[m] = b_labels[b * M + m];
    sobj[m] = objidx[b * M + m];
  }
  {  // coalesced float4 staging of this block's contiguous pred_cls slab
    const float4* src = (const float4*)(pred_cls + ((size_t)b * P + p0) * C);
    int nf4 = nact * C / 4;
    for (int i = tid; i < nf4; i += TPB2) ((float4*)sCls)[i] = src[i];
  }
  __syncthreads();

  float locpart = 0.0f, cepospart = 0.0f;
  int npos = 0;
  if (tid < nact) {
    int p = p0 + tid;
    float4 pr = ((const float4*)priors)[p];
    float pw2 = pr.z * 0.5f, ph2 = pr.w * 0.5f;
    float px1 = pr.x - pw2, py1 = pr.y - ph2;
    float px2 = pr.x + pw2, py2 = pr.y + ph2;
    float areaP = pr.z * pr.w;
    float best = -1.0f;
    int bm = 0;
#pragma unroll
    for (int m = 0; m < M; m++) {
      float iw = fminf(sx2[m], px2) - fmaxf(sx1[m], px1);
      float ih = fminf(sy2[m], py2) - fmaxf(sy1[m], py1);
      iw = fmaxf(iw, 0.0f);
      ih = fmaxf(ih, 0.0f);
      float inter = iw * ih;
      float iou = inter / (sarea[m] + areaP - inter);
      if (sobj[m] == p) iou = 1.0f;            // forced best-prior-per-object
      if (iou > best) { best = iou; bm = m; }  // first max (ascending m)
    }
    bool pos = best >= THRESH;
    int cls = pos ? slab[bm] : 0;

    float bx1 = sx1[bm], by1 = sy1[bm], bx2 = sx2[bm], by2 = sy2[bm];
    float cx = (bx1 + bx2) * 0.5f, cy = (by1 + by2) * 0.5f;
    float w = bx2 - bx1, h = by2 - by1;
    float g0 = (cx - pr.x) * 10.0f / pr.z;
    float g1 = (cy - pr.y) * 10.0f / pr.w;
    float g2 = logf(w / pr.z) * 5.0f;
    float g3 = logf(h / pr.w) * 5.0f;

    float4 pl = ((const float4*)pred_loc)[(size_t)b * P + p];
    if (pos) {
      locpart = fabsf(pl.x - g0) + fabsf(pl.y - g1) +
                fabsf(pl.z - g2) + fabsf(pl.w - g3);
      npos = 1;
    }

    const float* v = &sCls[tid * C];
    float mx = v[0];
#pragma unroll
    for (int c = 1; c < C; c++) mx = fmaxf(mx, v[c]);
    float se = 0.0f;
#pragma unroll
    for (int c = 0; c < C; c++) se += expf(v[c] - mx);
    float lse = mx + logf(se);
    float ce = lse - v[cls];

    confneg[(size_t)b * P + p] = pos ? 0.0f : ce;
    cepospart = pos ? ce : 0.0f;
  }

  for (int off = 32; off >= 1; off >>= 1) {
    locpart += __shfl_down(locpart, off, 64);
    cepospart += __shfl_down(cepospart, off, 64);
    npos += __shfl_down(npos, off, 64);
  }
  __shared__ float rloc[4], rce[4];
  __shared__ int rnp[4];
  int wid = tid >> 6;
  if ((tid & 63) == 0) { rloc[wid] = locpart; rce[wid] = cepospart; rnp[wid] = npos; }
  __syncthreads();
  if (tid == 0) {
    int f = b * NB2 + blockIdx.x;
    ploc[f] = rloc[0] + rloc[1] + rloc[2] + rloc[3];
    pce[f] = rce[0] + rce[1] + rce[2] + rce[3];
    pnp[f] = rnp[0] + rnp[1] + rnp[2] + rnp[3];
  }
}

// ---------------- k3: per-image exact top-K + finalize ----------------------
// radix-256 MSB-first select: per-wave privatized LDS histograms (low
// contention), single-wave shfl suffix-scan for digit selection (no serial
// loop, no extra barriers). Exact tie handling as sort-then-mask.
__global__ __launch_bounds__(1024) void k3_hardneg(
    const float* __restrict__ confneg,
    const float* __restrict__ ploc, const float* __restrict__ pce,
    const int* __restrict__ pnp,
    float* __restrict__ imgres, int* __restrict__ done,
    float* __restrict__ out) {
  int b = blockIdx.x;
  int tid = threadIdx.x;
  int wid = tid >> 6;
  int lane = tid & 63;

  __shared__ float s[P];                 // 34928 B
  __shared__ int histw[16 * 256];        // 16384 B per-wave histograms
  __shared__ __align__(16) int cnt[256];
  __shared__ int sdig, scum, sK;
  __shared__ float sLoc, sCe, sNp;
  __shared__ float rsum[16];
  __shared__ int rcnt[16];

  const float* row = confneg + (size_t)b * P;
  for (int i = tid; i < P; i += 1024) s[i] = row[i];

  if (wid == 0) {  // wave 0: reduce this image's per-block partials
    float lp = 0.0f, cp = 0.0f;
    int np = 0;
    if (lane < NB2) {
      int f = b * NB2 + lane;
      lp = ploc[f];
      cp = pce[f];
      np = pnp[f];
    }
    for (int off = 32; off >= 1; off >>= 1) {
      lp += __shfl_down(lp, off, 64);
      cp += __shfl_down(cp, off, 64);
      np += __shfl_down(np, off, 64);
    }
    if (lane == 0) {
      int K = np * 3;
      if (K > P) K = P;
      sK = K; sLoc = lp; sCe = cp; sNp = (float)np;
    }
  }
  __syncthreads();

  int K = sK;
  unsigned pfx = 0;
  int Krem = K;
#pragma unroll
  for (int pass = 3; pass >= 0; --pass) {
    int sh = pass * 8;
    for (int i = tid; i < 16 * 256; i += 1024) histw[i] = 0;
    __syncthreads();
    unsigned himask = (pass == 3) ? 0u : (0xFFFFFFFFu << (sh + 8));
    int* myh = &histw[wid * 256];
    for (int i = tid; i < P; i += 1024) {
      unsigned ub = __float_as_uint(s[i]);
      if ((ub & himask) == pfx) atomicAdd(&myh[(ub >> sh) & 255], 1);
    }
    __syncthreads();
    if (tid < 256) {
      int c = 0;
#pragma unroll
      for (int w = 0; w < 16; w++) c += histw[w * 256 + tid];
      cnt[tid] = c;
    }
    __syncthreads();
    if (wid == 0) {  // wave 0: digit selection via suffix scan
      int4 c4 = ((const int4*)cnt)[lane];  // bins 4L..4L+3
      int s3 = c4.w;
      int s2 = c4.z + s3;
      int s1 = c4.y + s2;
      int s0 = c4.x + s1;  // suffix sums within lane's 4 bins
      int suf = s0;        // inclusive suffix over lanes >= L
      for (int off = 1; off < 64; off <<= 1) {
        int t = __shfl_down(suf, off, 64);
        if (lane + off < 64) suf += t;
      }
      int above = suf - s0;  // sum over lanes > L
      int S0 = above + s0, S1 = above + s1, S2 = above + s2, S3 = above + s3;
      int S4 = above;  // = S[4L+4]; for lane 63 this is 0 == S[256]
      // chosen d: largest with S[d] >= Krem  <=>  S[d]>=Krem && S[d+1]<Krem
      if (S3 >= Krem && S4 < Krem) { sdig = 4 * lane + 3; scum = S4; }
      else if (S2 >= Krem && S3 < Krem) { sdig = 4 * lane + 2; scum = S3; }
      else if (S1 >= Krem && S2 < Krem) { sdig = 4 * lane + 1; scum = S2; }
      else if (S0 >= Krem && S1 < Krem) { sdig = 4 * lane + 0; scum = S1; }
    }
    __syncthreads();
    pfx |= ((unsigned)sdig) << sh;
    Krem -= scum;
  }
  float tau = __uint_as_float(pfx);  // exact K-th largest value

  float sum = 0.0f;
  int cgt = 0;
  for (int i = tid; i < P; i += 1024) {
    float v = s[i];
    if (v > tau) { sum += v; cgt++; }
  }
  for (int off = 32; off >= 1; off >>= 1) {
    sum += __shfl_down(sum, off, 64);
    cgt += __shfl_down(cgt, off, 64);
  }
  if (lane == 0) { rsum[wid] = sum; rcnt[wid] = cgt; }
  __syncthreads();
  if (tid == 0) {
    float stot = 0.0f;
    int ctot = 0;
#pragma unroll
    for (int w = 0; w < 16; w++) { stot += rsum[w]; ctot += rcnt[w]; }
    float hard = stot + (float)(K - ctot) * tau;  // exact tie handling
    imgres[b * 4 + 0] = sLoc;
    imgres[b * 4 + 1] = sCe;
    imgres[b * 4 + 2] = hard;
    imgres[b * 4 + 3] = sNp;
    __threadfence();
    int prev = atomicAdd(done, 1);
    if (prev == B - 1) {  // last block finalizes
      __threadfence();
      float l = 0.0f, c = 0.0f, h = 0.0f, n = 0.0f;
      for (int im = 0; im < B; im++) {  // atomic loads for cross-XCD safety
        l += atomicAdd(&imgres[im * 4 + 0], 0.0f);
        c += atomicAdd(&imgres[im * 4 + 1], 0.0f);
        h += atomicAdd(&imgres[im * 4 + 2], 0.0f);
        n += atomicAdd(&imgres[im * 4 + 3], 0.0f);
      }
      float loc = ALPHA * l / (n * 4.0f);
      float conf = (h + c) / n;
      out[0] = conf + loc;
      out[1] = loc;
      out[2] = conf;
    }
  }
}

extern "C" void kernel_launch(void* const* d_in, const int* in_sizes, int n_in,
                              void* d_out, int out_size, void* d_ws, size_t ws_size,
                              hipStream_t stream) {
  (void)in_sizes; (void)n_in; (void)out_size; (void)ws_size;
  const float* pred_loc = (const float*)d_in[0];
  const float* pred_cls = (const float*)d_in[1];
  const float* b_boxes = (const float*)d_in[2];
  const int* b_labels = (const int*)d_in[3];
  const float* priors = (const float*)d_in[4];
  float* out = (float*)d_out;

  // ws layout (4B units):
  // [0] done counter | [8..) ploc[B*NB2] | pce[B*NB2] | pnp[B*NB2] (int)
  // | imgres[B*4] | objidx[B*M] (int) | confneg[B*P]
  int* done = (int*)d_ws;
  float* ploc = (float*)d_ws + 8;
  float* pce = ploc + B * NB2;
  int* pnp = (int*)(pce + B * NB2);
  float* imgres = (float*)(pnp + B * NB2);
  int* objidx = (int*)(imgres + B * 4);
  float* confneg = (float*)(objidx + B * M);

  hipMemsetAsync(d_ws, 0, 32, stream);

  k1_objargmax<<<(B * M + 3) / 4, 256, 0, stream>>>(b_boxes, priors, objidx);
  dim3 g2(NB2, B);
  k2_perprior<<<g2, TPB2, 0, stream>>>(pred_loc, pred_cls, b_boxes, b_labels,
                                       priors, objidx, ploc, pce, pnp, confneg);
  k3_hardneg<<<B, 1024, 0, stream>>>(confneg, ploc, pce, pnp, imgres, done, out);
}

// Round 4
// 291.419 us; speedup vs baseline: 1.5266x; 1.5266x over previous
//
#include <hip/hip_runtime.h>
#include <math.h>

#define B 128
#define M 32
#define P 8732
#define C 21
#define ALPHA 10.0f
#define TPB2 256
#define PPT 4            // priors per thread in k2
#define PPB (TPB2 * PPT) // 1024 priors per block
#define NB2 9            // ceil(P / PPB); note P = 4*2183 so PPT always full

// ---------------- k1: best prior per object (obj_idx) -----------------------
__global__ __launch_bounds__(256) void k1_objargmax(
    const float* __restrict__ b_boxes, const float* __restrict__ priors,
    int* __restrict__ objidx) {
  int wid = threadIdx.x >> 6;
  int lane = threadIdx.x & 63;
  int task = blockIdx.x * 4 + wid;  // (b*M + m)
  if (task >= B * M) return;
  const float* bx = b_boxes + (size_t)task * 4;
  float x1 = bx[0], y1 = bx[1], x2 = bx[2], y2 = bx[3];
  float areaA = (x2 - x1) * (y2 - y1);
  float best = -1.0f;
  int bi = P;
  for (int p = lane; p < P; p += 64) {
    float4 pr = ((const float4*)priors)[p];
    float pw2 = pr.z * 0.5f, ph2 = pr.w * 0.5f;
    float iw = fminf(x2, pr.x + pw2) - fmaxf(x1, pr.x - pw2);
    float ih = fminf(y2, pr.y + ph2) - fmaxf(y1, pr.y - ph2);
    iw = fmaxf(iw, 0.0f);
    ih = fmaxf(ih, 0.0f);
    float inter = iw * ih;
    float iou = inter / (areaA + pr.z * pr.w - inter);
    if (iou > best) { best = iou; bi = p; }  // strict > keeps smallest p
  }
  for (int off = 32; off >= 1; off >>= 1) {
    float ov = __shfl_xor(best, off, 64);
    int oi = __shfl_xor(bi, off, 64);
    if (ov > best || (ov == best && oi < bi)) { best = ov; bi = oi; }
  }
  if (lane == 0) objidx[task] = bi;
}

// ---------------- k2: per-prior match + loc partial + CE --------------------
// 4 consecutive priors per thread: 16B-aligned float4 reads of pred_cls
// (thread base = 84*tid floats), 4 independent compute chains for ILP,
// no LDS staging barrier, no global atomics.
__global__ __launch_bounds__(TPB2) void k2_perprior(
    const float* __restrict__ pred_loc, const float* __restrict__ pred_cls,
    const float* __restrict__ b_boxes, const int* __restrict__ b_labels,
    const float* __restrict__ priors, const int* __restrict__ objidx,
    float* __restrict__ ploc, float* __restrict__ pce, int* __restrict__ pnp,
    float* __restrict__ confneg) {
  int b = blockIdx.y;
  int p0 = blockIdx.x * PPB;
  int tid = threadIdx.x;

  __shared__ float sx1[M], sy1[M], sx2[M], sy2[M], sarea[M];
  __shared__ int slab[M], sobj[M];
  if (tid < M) {
    int m = tid;
    float4 bx = ((const float4*)b_boxes)[b * M + m];
    sx1[m] = bx.x; sy1[m] = bx.y; sx2[m] = bx.z; sy2[m] = bx.w;
    sarea[m] = (bx.z - bx.x) * (bx.w - bx.y);
    slab[m] = b_labels[b * M + m];
    sobj[m] = objidx[b * M + m];
  }
  __syncthreads();

  float locpart = 0.0f, cepospart = 0.0f;
  int npos = 0;
  int pbase = p0 + tid * PPT;
  if (pbase < P) {
    float4 pr[PPT], pl[PPT];
    const float4* prp = (const float4*)priors + pbase;
    const float4* plp = (const float4*)pred_loc + (size_t)b * P + pbase;
#pragma unroll
    for (int j = 0; j < PPT; j++) { pr[j] = prp[j]; pl[j] = plp[j]; }

    float px1[PPT], py1[PPT], px2[PPT], py2[PPT], areaP[PPT], best[PPT];
    int bm[PPT];
#pragma unroll
    for (int j = 0; j < PPT; j++) {
      float pw2 = pr[j].z * 0.5f, ph2 = pr[j].w * 0.5f;
      px1[j] = pr[j].x - pw2; py1[j] = pr[j].y - ph2;
      px2[j] = pr[j].x + pw2; py2[j] = pr[j].y + ph2;
      areaP[j] = pr[j].z * pr[j].w;
      best[j] = -1.0f; bm[j] = 0;
    }
    for (int m = 0; m < M; m++) {
      float bx1 = sx1[m], by1 = sy1[m], bx2 = sx2[m], by2 = sy2[m];
      float ar = sarea[m];
      int so = sobj[m];
#pragma unroll
      for (int j = 0; j < PPT; j++) {
        float iw = fminf(bx2, px2[j]) - fmaxf(bx1, px1[j]);
        float ih = fminf(by2, py2[j]) - fmaxf(by1, py1[j]);
        iw = fmaxf(iw, 0.0f);
        ih = fmaxf(ih, 0.0f);
        float inter = iw * ih;
        float iou = inter / (ar + areaP[j] - inter);
        if (so == pbase + j) iou = 1.0f;             // forced best prior
        if (iou > best[j]) { best[j] = iou; bm[j] = m; }  // first max
      }
    }

    // per-thread class base: float offset 84*tid within block slab (16B aligned)
    const float4* pc4t =
        (const float4*)(pred_cls + ((size_t)b * P + p0) * C) + 21 * tid;
    float4 cn;
    float* cnp = (float*)&cn;
#pragma unroll
    for (int j = 0; j < PPT; j++) {
      bool pos = best[j] >= 0.5f;
      int mj = bm[j];
      int cls = pos ? slab[mj] : 0;
      float bx1 = sx1[mj], by1 = sy1[mj], bx2 = sx2[mj], by2 = sy2[mj];
      float cx = (bx1 + bx2) * 0.5f, cy = (by1 + by2) * 0.5f;
      float w = bx2 - bx1, h = by2 - by1;
      float g0 = (cx - pr[j].x) * 10.0f / pr[j].z;
      float g1 = (cy - pr[j].y) * 10.0f / pr[j].w;
      float g2 = logf(w / pr[j].z) * 5.0f;
      float g3 = logf(h / pr[j].w) * 5.0f;
      if (pos) {
        locpart += fabsf(pl[j].x - g0) + fabsf(pl[j].y - g1) +
                   fabsf(pl[j].z - g2) + fabsf(pl[j].w - g3);
        npos++;
      }
      // prior j's 21 classes live at thread-local floats 21j..21j+20,
      // covered by float4s [5j..5j+5] with in-window offset j.
      float4 u4[6];
#pragma unroll
      for (int q = 0; q < 6; q++) u4[q] = pc4t[5 * j + q];
      const float* u = (const float*)u4;
      float mx = u[j];
#pragma unroll
      for (int c = 1; c < C; c++) mx = fmaxf(mx, u[j + c]);
      float se = 0.0f;
#pragma unroll
      for (int c = 0; c < C; c++) se += expf(u[j + c] - mx);
      float ce = mx + logf(se) - u[j + cls];
      cnp[j] = pos ? 0.0f : ce;
      cepospart += pos ? ce : 0.0f;
    }
    ((float4*)confneg)[((size_t)b * P + pbase) >> 2] = cn;
  }

  for (int off = 32; off >= 1; off >>= 1) {
    locpart += __shfl_down(locpart, off, 64);
    cepospart += __shfl_down(cepospart, off, 64);
    npos += __shfl_down(npos, off, 64);
  }
  __shared__ float rloc[4], rce[4];
  __shared__ int rnp[4];
  int wid = tid >> 6;
  if ((tid & 63) == 0) { rloc[wid] = locpart; rce[wid] = cepospart; rnp[wid] = npos; }
  __syncthreads();
  if (tid == 0) {
    int f = b * NB2 + blockIdx.x;
    ploc[f] = rloc[0] + rloc[1] + rloc[2] + rloc[3];
    pce[f] = rce[0] + rce[1] + rce[2] + rce[3];
    pnp[f] = rnp[0] + rnp[1] + rnp[2] + rnp[3];
  }
}

// ---------------- k3: per-image exact top-K + PARALLEL finalize -------------
__global__ __launch_bounds__(1024) void k3_hardneg(
    const float* __restrict__ confneg,
    const float* __restrict__ ploc, const float* __restrict__ pce,
    const int* __restrict__ pnp,
    float* __restrict__ imgres, int* __restrict__ done,
    float* __restrict__ out) {
  int b = blockIdx.x;
  int tid = threadIdx.x;
  int wid = tid >> 6;
  int lane = tid & 63;

  __shared__ float s[P];                 // 34928 B
  __shared__ int histw[16 * 256];        // per-wave histograms
  __shared__ __align__(16) int cnt[256];
  __shared__ int sdig, scum, sK, sLast;
  __shared__ float sLoc, sCe, sNp;
  __shared__ float rsum[16], rl[16], rc[16], rh[16], rn[16];
  __shared__ int rcnt[16];

  const float* row = confneg + (size_t)b * P;
  for (int i = tid; i < P; i += 1024) s[i] = row[i];

  if (wid == 0) {  // wave 0: reduce this image's 9 per-block partials
    float lp = 0.0f, cp = 0.0f;
    int np = 0;
    if (lane < NB2) {
      int f = b * NB2 + lane;
      lp = ploc[f]; cp = pce[f]; np = pnp[f];
    }
    for (int off = 32; off >= 1; off >>= 1) {
      lp += __shfl_down(lp, off, 64);
      cp += __shfl_down(cp, off, 64);
      np += __shfl_down(np, off, 64);
    }
    if (lane == 0) {
      int K = np * 3;
      if (K > P) K = P;
      sK = K; sLoc = lp; sCe = cp; sNp = (float)np;
    }
  }
  __syncthreads();

  int K = sK;
  unsigned pfx = 0;
  int Krem = K;
#pragma unroll
  for (int pass = 3; pass >= 0; --pass) {
    int sh = pass * 8;
    for (int i = tid; i < 16 * 256; i += 1024) histw[i] = 0;
    __syncthreads();
    unsigned himask = (pass == 3) ? 0u : (0xFFFFFFFFu << (sh + 8));
    int* myh = &histw[wid * 256];
    for (int i = tid; i < P; i += 1024) {
      unsigned ub = __float_as_uint(s[i]);
      if ((ub & himask) == pfx) atomicAdd(&myh[(ub >> sh) & 255], 1);
    }
    __syncthreads();
    if (tid < 256) {
      int c = 0;
#pragma unroll
      for (int w = 0; w < 16; w++) c += histw[w * 256 + tid];
      cnt[tid] = c;
    }
    __syncthreads();
    if (wid == 0) {  // digit selection via wave suffix-scan
      int4 c4 = ((const int4*)cnt)[lane];
      int s3 = c4.w;
      int s2 = c4.z + s3;
      int s1 = c4.y + s2;
      int s0 = c4.x + s1;
      int suf = s0;
      for (int off = 1; off < 64; off <<= 1) {
        int t = __shfl_down(suf, off, 64);
        if (lane + off < 64) suf += t;
      }
      int above = suf - s0;
      int S0 = above + s0, S1 = above + s1, S2 = above + s2, S3 = above + s3;
      int S4 = above;
      if (S3 >= Krem && S4 < Krem) { sdig = 4 * lane + 3; scum = S4; }
      else if (S2 >= Krem && S3 < Krem) { sdig = 4 * lane + 2; scum = S3; }
      else if (S1 >= Krem && S2 < Krem) { sdig = 4 * lane + 1; scum = S2; }
      else if (S0 >= Krem && S1 < Krem) { sdig = 4 * lane + 0; scum = S1; }
    }
    __syncthreads();
    pfx |= ((unsigned)sdig) << sh;
    Krem -= scum;
  }
  float tau = __uint_as_float(pfx);  // exact K-th largest value

  float sum = 0.0f;
  int cgt = 0;
  for (int i = tid; i < P; i += 1024) {
    float v = s[i];
    if (v > tau) { sum += v; cgt++; }
  }
  for (int off = 32; off >= 1; off >>= 1) {
    sum += __shfl_down(sum, off, 64);
    cgt += __shfl_down(cgt, off, 64);
  }
  if (lane == 0) { rsum[wid] = sum; rcnt[wid] = cgt; }
  __syncthreads();
  if (tid == 0) {
    float stot = 0.0f;
    int ctot = 0;
#pragma unroll
    for (int w = 0; w < 16; w++) { stot += rsum[w]; ctot += rcnt[w]; }
    float hard = stot + (float)(K - ctot) * tau;  // exact tie handling
    imgres[b * 4 + 0] = sLoc;
    imgres[b * 4 + 1] = sCe;
    imgres[b * 4 + 2] = hard;
    imgres[b * 4 + 3] = sNp;
    __threadfence();
    int prev = atomicAdd(done, 1);
    sLast = (prev == B - 1) ? 1 : 0;
  }
  __syncthreads();
  if (sLast) {  // last block: PARALLEL finalize (one image per thread)
    __threadfence();
    float l = 0.0f, c = 0.0f, h = 0.0f, n = 0.0f;
    if (tid < B) {
      l = atomicAdd(&imgres[tid * 4 + 0], 0.0f);
      c = atomicAdd(&imgres[tid * 4 + 1], 0.0f);
      h = atomicAdd(&imgres[tid * 4 + 2], 0.0f);
      n = atomicAdd(&imgres[tid * 4 + 3], 0.0f);
    }
    for (int off = 32; off >= 1; off >>= 1) {
      l += __shfl_down(l, off, 64);
      c += __shfl_down(c, off, 64);
      h += __shfl_down(h, off, 64);
      n += __shfl_down(n, off, 64);
    }
    if (lane == 0) { rl[wid] = l; rc[wid] = c; rh[wid] = h; rn[wid] = n; }
    __syncthreads();
    if (tid == 0) {
      float L = 0, Cc = 0, H = 0, N = 0;
#pragma unroll
      for (int w = 0; w < 16; w++) { L += rl[w]; Cc += rc[w]; H += rh[w]; N += rn[w]; }
      float loc = ALPHA * L / (N * 4.0f);
      float conf = (H + Cc) / N;
      out[0] = conf + loc;
      out[1] = loc;
      out[2] = conf;
    }
  }
}

extern "C" void kernel_launch(void* const* d_in, const int* in_sizes, int n_in,
                              void* d_out, int out_size, void* d_ws, size_t ws_size,
                              hipStream_t stream) {
  (void)in_sizes; (void)n_in; (void)out_size; (void)ws_size;
  const float* pred_loc = (const float*)d_in[0];
  const float* pred_cls = (const float*)d_in[1];
  const float* b_boxes = (const float*)d_in[2];
  const int* b_labels = (const int*)d_in[3];
  const float* priors = (const float*)d_in[4];
  float* out = (float*)d_out;

  // ws layout (4B units):
  // [0] done | [8..) ploc[B*NB2] | pce[B*NB2] | pnp[B*NB2] | imgres[B*4]
  // | objidx[B*M] | confneg[B*P]
  int* done = (int*)d_ws;
  float* ploc = (float*)d_ws + 8;
  float* pce = ploc + B * NB2;
  int* pnp = (int*)(pce + B * NB2);
  float* imgres = (float*)(pnp + B * NB2);
  int* objidx = (int*)(imgres + B * 4);
  float* confneg = (float*)(objidx + B * M);

  hipMemsetAsync(d_ws, 0, 32, stream);

  k1_objargmax<<<(B * M + 3) / 4, 256, 0, stream>>>(b_boxes, priors, objidx);
  dim3 g2(NB2, B);
  k2_perprior<<<g2, TPB2, 0, stream>>>(pred_loc, pred_cls, b_boxes, b_labels,
                                       priors, objidx, ploc, pce, pnp, confneg);
  k3_hardneg<<<B, 1024, 0, stream>>>(confneg, ploc, pce, pnp, imgres, done, out);
}

// Round 5
// 259.354 us; speedup vs baseline: 1.7154x; 1.1236x over previous
//
#include <hip/hip_runtime.h>
#include <math.h>

#define B 128
#define M 32
#define P 8732
#define C 21
#define ALPHA 10.0f
#define TPB2 256
#define PPT 4            // priors per thread in k2
#define PPB (TPB2 * PPT) // 1024 priors per block
#define NB2 9            // ceil(P / PPB)

// ---------------- k1: best prior per object (obj_idx) -----------------------
// also zeroes the k3 'done' counter (ws is re-poisoned to 0xAA every launch)
__global__ __launch_bounds__(256) void k1_objargmax(
    const float* __restrict__ b_boxes, const float* __restrict__ priors,
    int* __restrict__ objidx, int* __restrict__ done) {
  if (blockIdx.x == 0 && threadIdx.x == 0) *done = 0;
  int wid = threadIdx.x >> 6;
  int lane = threadIdx.x & 63;
  int task = blockIdx.x * 4 + wid;  // (b*M + m)
  if (task >= B * M) return;
  const float* bx = b_boxes + (size_t)task * 4;
  float x1 = bx[0], y1 = bx[1], x2 = bx[2], y2 = bx[3];
  float areaA = (x2 - x1) * (y2 - y1);
  float best = -1.0f;
  int bi = P;
  for (int p = lane; p < P; p += 64) {
    float4 pr = ((const float4*)priors)[p];
    float pw2 = pr.z * 0.5f, ph2 = pr.w * 0.5f;
    float iw = fminf(x2, pr.x + pw2) - fmaxf(x1, pr.x - pw2);
    float ih = fminf(y2, pr.y + ph2) - fmaxf(y1, pr.y - ph2);
    iw = fmaxf(iw, 0.0f);
    ih = fmaxf(ih, 0.0f);
    float inter = iw * ih;
    float iou = inter / (areaA + pr.z * pr.w - inter);
    if (iou > best) { best = iou; bi = p; }  // strict > keeps smallest p
  }
  for (int off = 32; off >= 1; off >>= 1) {
    float ov = __shfl_xor(best, off, 64);
    int oi = __shfl_xor(bi, off, 64);
    if (ov > best || (ov == best && oi < bi)) { best = ov; bi = oi; }
  }
  if (lane == 0) objidx[task] = bi;
}

// ---------------- k2: per-prior match + loc partial + CE --------------------
// 4 consecutive priors/thread, float4 class reads, NO dynamic register-array
// indexing (cls extracted via predicated select -> no scratch spill).
__global__ __launch_bounds__(TPB2) void k2_perprior(
    const float* __restrict__ pred_loc, const float* __restrict__ pred_cls,
    const float* __restrict__ b_boxes, const int* __restrict__ b_labels,
    const float* __restrict__ priors, const int* __restrict__ objidx,
    float* __restrict__ ploc, float* __restrict__ pce, int* __restrict__ pnp,
    float* __restrict__ confneg) {
  int b = blockIdx.y;
  int p0 = blockIdx.x * PPB;
  int tid = threadIdx.x;

  __shared__ float sx1[M], sy1[M], sx2[M], sy2[M], sarea[M];
  __shared__ int slab[M], sobj[M];
  if (tid < M) {
    int m = tid;
    float4 bx = ((const float4*)b_boxes)[b * M + m];
    sx1[m] = bx.x; sy1[m] = bx.y; sx2[m] = bx.z; sy2[m] = bx.w;
    sarea[m] = (bx.z - bx.x) * (bx.w - bx.y);
    slab[m] = b_labels[b * M + m];
    sobj[m] = objidx[b * M + m];
  }
  __syncthreads();

  float locpart = 0.0f, cepospart = 0.0f;
  int npos = 0;
  int pbase = p0 + tid * PPT;
  if (pbase < P) {
    float4 pr[PPT], pl[PPT];
    const float4* prp = (const float4*)priors + pbase;
    const float4* plp = (const float4*)pred_loc + (size_t)b * P + pbase;
#pragma unroll
    for (int j = 0; j < PPT; j++) { pr[j] = prp[j]; pl[j] = plp[j]; }

    float px1[PPT], py1[PPT], px2[PPT], py2[PPT], areaP[PPT], best[PPT];
    int bm[PPT];
#pragma unroll
    for (int j = 0; j < PPT; j++) {
      float pw2 = pr[j].z * 0.5f, ph2 = pr[j].w * 0.5f;
      px1[j] = pr[j].x - pw2; py1[j] = pr[j].y - ph2;
      px2[j] = pr[j].x + pw2; py2[j] = pr[j].y + ph2;
      areaP[j] = pr[j].z * pr[j].w;
      best[j] = -1.0f; bm[j] = 0;
    }
    for (int m = 0; m < M; m++) {
      float bx1 = sx1[m], by1 = sy1[m], bx2 = sx2[m], by2 = sy2[m];
      float ar = sarea[m];
      int so = sobj[m];
#pragma unroll
      for (int j = 0; j < PPT; j++) {
        float iw = fminf(bx2, px2[j]) - fmaxf(bx1, px1[j]);
        float ih = fminf(by2, py2[j]) - fmaxf(by1, py1[j]);
        iw = fmaxf(iw, 0.0f);
        ih = fmaxf(ih, 0.0f);
        float inter = iw * ih;
        float iou = inter / (ar + areaP[j] - inter);
        if (so == pbase + j) iou = 1.0f;             // forced best prior
        if (iou > best[j]) { best[j] = iou; bm[j] = m; }  // first max
      }
    }

    // per-thread class base: float offset 84*tid within block slab (16B aligned)
    const float4* pc4t =
        (const float4*)(pred_cls + ((size_t)b * P + p0) * C) + 21 * tid;
    float4 cn;
    float* cnp = (float*)&cn;
#pragma unroll
    for (int j = 0; j < PPT; j++) {
      bool pos = best[j] >= 0.5f;
      int mj = bm[j];
      int cls = pos ? slab[mj] : 0;
      float bx1 = sx1[mj], by1 = sy1[mj], bx2 = sx2[mj], by2 = sy2[mj];
      float cx = (bx1 + bx2) * 0.5f, cy = (by1 + by2) * 0.5f;
      float w = bx2 - bx1, h = by2 - by1;
      float g0 = (cx - pr[j].x) * 10.0f / pr[j].z;
      float g1 = (cy - pr[j].y) * 10.0f / pr[j].w;
      float g2 = __logf(w / pr[j].z) * 5.0f;
      float g3 = __logf(h / pr[j].w) * 5.0f;
      if (pos) {
        locpart += fabsf(pl[j].x - g0) + fabsf(pl[j].y - g1) +
                   fabsf(pl[j].z - g2) + fabsf(pl[j].w - g3);
        npos++;
      }
      // prior j's 21 classes: thread-local floats 21j..21j+20 ->
      // float4s [5j..5j+5], in-window offset j. ALL indices below are
      // compile-time constants after unroll (no scratch).
      float4 u4[6];
#pragma unroll
      for (int q = 0; q < 6; q++) u4[q] = pc4t[5 * j + q];
      const float* u = (const float*)u4;
      float mx = u[j];
#pragma unroll
      for (int c = 1; c < C; c++) mx = fmaxf(mx, u[j + c]);
      float se = 0.0f;
      float vc = u[j];  // class 0 default
#pragma unroll
      for (int c = 0; c < C; c++) {
        float x = u[j + c];
        se += __expf(x - mx);
        if (c == cls) vc = x;  // predicated select, constant index
      }
      float ce = mx + __logf(se) - vc;
      cnp[j] = pos ? 0.0f : ce;
      cepospart += pos ? ce : 0.0f;
    }
    ((float4*)confneg)[((size_t)b * P + pbase) >> 2] = cn;
  }

  for (int off = 32; off >= 1; off >>= 1) {
    locpart += __shfl_down(locpart, off, 64);
    cepospart += __shfl_down(cepospart, off, 64);
    npos += __shfl_down(npos, off, 64);
  }
  __shared__ float rloc[4], rce[4];
  __shared__ int rnp[4];
  int wid = tid >> 6;
  if ((tid & 63) == 0) { rloc[wid] = locpart; rce[wid] = cepospart; rnp[wid] = npos; }
  __syncthreads();
  if (tid == 0) {
    int f = b * NB2 + blockIdx.x;
    ploc[f] = rloc[0] + rloc[1] + rloc[2] + rloc[3];
    pce[f] = rce[0] + rce[1] + rce[2] + rce[3];
    pnp[f] = rnp[0] + rnp[1] + rnp[2] + rnp[3];
  }
}

// ---------------- k3: per-image exact top-K + parallel finalize -------------
__global__ __launch_bounds__(1024) void k3_hardneg(
    const float* __restrict__ confneg,
    const float* __restrict__ ploc, const float* __restrict__ pce,
    const int* __restrict__ pnp,
    float* __restrict__ imgres, int* __restrict__ done,
    float* __restrict__ out) {
  int b = blockIdx.x;
  int tid = threadIdx.x;
  int wid = tid >> 6;
  int lane = tid & 63;

  __shared__ float s[P];                 // 34928 B
  __shared__ int histw[16 * 256];        // per-wave histograms
  __shared__ __align__(16) int cnt[256];
  __shared__ int sdig, scum, sK, sLast;
  __shared__ float sLoc, sCe, sNp;
  __shared__ float rsum[16], rl[16], rc[16], rh[16], rn[16];
  __shared__ int rcnt[16];

  const float* row = confneg + (size_t)b * P;
  for (int i = tid; i < P; i += 1024) s[i] = row[i];

  if (wid == 0) {  // wave 0: reduce this image's 9 per-block partials
    float lp = 0.0f, cp = 0.0f;
    int np = 0;
    if (lane < NB2) {
      int f = b * NB2 + lane;
      lp = ploc[f]; cp = pce[f]; np = pnp[f];
    }
    for (int off = 32; off >= 1; off >>= 1) {
      lp += __shfl_down(lp, off, 64);
      cp += __shfl_down(cp, off, 64);
      np += __shfl_down(np, off, 64);
    }
    if (lane == 0) {
      int K = np * 3;
      if (K > P) K = P;
      sK = K; sLoc = lp; sCe = cp; sNp = (float)np;
    }
  }
  __syncthreads();

  int K = sK;
  unsigned pfx = 0;
  int Krem = K;
#pragma unroll
  for (int pass = 3; pass >= 0; --pass) {
    int sh = pass * 8;
    for (int i = tid; i < 16 * 256; i += 1024) histw[i] = 0;
    __syncthreads();
    unsigned himask = (pass == 3) ? 0u : (0xFFFFFFFFu << (sh + 8));
    int* myh = &histw[wid * 256];
    for (int i = tid; i < P; i += 1024) {
      unsigned ub = __float_as_uint(s[i]);
      if ((ub & himask) == pfx) atomicAdd(&myh[(ub >> sh) & 255], 1);
    }
    __syncthreads();
    if (tid < 256) {
      int c = 0;
#pragma unroll
      for (int w = 0; w < 16; w++) c += histw[w * 256 + tid];
      cnt[tid] = c;
    }
    __syncthreads();
    if (wid == 0) {  // digit selection via wave suffix-scan
      int4 c4 = ((const int4*)cnt)[lane];
      int s3 = c4.w;
      int s2 = c4.z + s3;
      int s1 = c4.y + s2;
      int s0 = c4.x + s1;
      int suf = s0;
      for (int off = 1; off < 64; off <<= 1) {
        int t = __shfl_down(suf, off, 64);
        if (lane + off < 64) suf += t;
      }
      int above = suf - s0;
      int S0 = above + s0, S1 = above + s1, S2 = above + s2, S3 = above + s3;
      int S4 = above;
      if (S3 >= Krem && S4 < Krem) { sdig = 4 * lane + 3; scum = S4; }
      else if (S2 >= Krem && S3 < Krem) { sdig = 4 * lane + 2; scum = S3; }
      else if (S1 >= Krem && S2 < Krem) { sdig = 4 * lane + 1; scum = S2; }
      else if (S0 >= Krem && S1 < Krem) { sdig = 4 * lane + 0; scum = S1; }
    }
    __syncthreads();
    pfx |= ((unsigned)sdig) << sh;
    Krem -= scum;
  }
  float tau = __uint_as_float(pfx);  // exact K-th largest value

  float sum = 0.0f;
  int cgt = 0;
  for (int i = tid; i < P; i += 1024) {
    float v = s[i];
    if (v > tau) { sum += v; cgt++; }
  }
  for (int off = 32; off >= 1; off >>= 1) {
    sum += __shfl_down(sum, off, 64);
    cgt += __shfl_down(cgt, off, 64);
  }
  if (lane == 0) { rsum[wid] = sum; rcnt[wid] = cgt; }
  __syncthreads();
  if (tid == 0) {
    float stot = 0.0f;
    int ctot = 0;
#pragma unroll
    for (int w = 0; w < 16; w++) { stot += rsum[w]; ctot += rcnt[w]; }
    float hard = stot + (float)(K - ctot) * tau;  // exact tie handling
    imgres[b * 4 + 0] = sLoc;
    imgres[b * 4 + 1] = sCe;
    imgres[b * 4 + 2] = hard;
    imgres[b * 4 + 3] = sNp;
    __threadfence();
    int prev = atomicAdd(done, 1);
    sLast = (prev == B - 1) ? 1 : 0;
  }
  __syncthreads();
  if (sLast) {  // last block: parallel finalize (one image per thread)
    __threadfence();
    float l = 0.0f, c = 0.0f, h = 0.0f, n = 0.0f;
    if (tid < B) {
      l = atomicAdd(&imgres[tid * 4 + 0], 0.0f);
      c = atomicAdd(&imgres[tid * 4 + 1], 0.0f);
      h = atomicAdd(&imgres[tid * 4 + 2], 0.0f);
      n = atomicAdd(&imgres[tid * 4 + 3], 0.0f);
    }
    for (int off = 32; off >= 1; off >>= 1) {
      l += __shfl_down(l, off, 64);
      c += __shfl_down(c, off, 64);
      h += __shfl_down(h, off, 64);
      n += __shfl_down(n, off, 64);
    }
    if (lane == 0) { rl[wid] = l; rc[wid] = c; rh[wid] = h; rn[wid] = n; }
    __syncthreads();
    if (tid == 0) {
      float L = 0, Cc = 0, H = 0, N = 0;
#pragma unroll
      for (int w = 0; w < 16; w++) { L += rl[w]; Cc += rc[w]; H += rh[w]; N += rn[w]; }
      float loc = ALPHA * L / (N * 4.0f);
      float conf = (H + Cc) / N;
      out[0] = conf + loc;
      out[1] = loc;
      out[2] = conf;
    }
  }
}

extern "C" void kernel_launch(void* const* d_in, const int* in_sizes, int n_in,
                              void* d_out, int out_size, void* d_ws, size_t ws_size,
                              hipStream_t stream) {
  (void)in_sizes; (void)n_in; (void)out_size; (void)ws_size;
  const float* pred_loc = (const float*)d_in[0];
  const float* pred_cls = (const float*)d_in[1];
  const float* b_boxes = (const float*)d_in[2];
  const int* b_labels = (const int*)d_in[3];
  const float* priors = (const float*)d_in[4];
  float* out = (float*)d_out;

  // ws layout (4B units):
  // [0] done | [8..) ploc[B*NB2] | pce[B*NB2] | pnp[B*NB2] | imgres[B*4]
  // | objidx[B*M] | confneg[B*P]
  int* done = (int*)d_ws;
  float* ploc = (float*)d_ws + 8;
  float* pce = ploc + B * NB2;
  int* pnp = (int*)(pce + B * NB2);
  float* imgres = (float*)(pnp + B * NB2);
  int* objidx = (int*)(imgres + B * 4);
  float* confneg = (float*)(objidx + B * M);

  k1_objargmax<<<(B * M + 3) / 4, 256, 0, stream>>>(b_boxes, priors, objidx, done);
  dim3 g2(NB2, B);
  k2_perprior<<<g2, TPB2, 0, stream>>>(pred_loc, pred_cls, b_boxes, b_labels,
                                       priors, objidx, ploc, pce, pnp, confneg);
  k3_hardneg<<<B, 1024, 0, stream>>>(confneg, ploc, pce, pnp, imgres, done, out);
}

// Round 6
// 227.308 us; speedup vs baseline: 1.9572x; 1.1410x over previous
//
#include <hip/hip_runtime.h>
#include <math.h>

#define B 128
#define M 32
#define P 8732
#define C 21
#define ALPHA 10.0f
#define TPB2 256
#define PPT 4            // priors per thread in k2
#define PPB (TPB2 * PPT) // 1024 priors per block
#define NB2 9            // ceil(P / PPB)

// ---------------- k1: best prior per object (obj_idx) -----------------------
// v2: 2 objects per wave (amortize prior loads) + unroll-4 (pipeline L2
// latency). Grid B*4 blocks x 256. IoU arithmetic identical to v1 (passing).
__global__ __launch_bounds__(256) void k1_objargmax(
    const float* __restrict__ b_boxes, const float* __restrict__ priors,
    int* __restrict__ objidx, int* __restrict__ done) {
  if (blockIdx.x == 0 && threadIdx.x == 0) *done = 0;
  int wid = threadIdx.x >> 6;
  int lane = threadIdx.x & 63;
  int b = blockIdx.x >> 2;
  int obase = ((blockIdx.x & 3) * 4 + wid) * 2;  // objects obase, obase+1

  const float* bxp = b_boxes + ((size_t)b * M + obase) * 4;
  float ax1 = bxp[0], ay1 = bxp[1], ax2 = bxp[2], ay2 = bxp[3];
  float bx1 = bxp[4], by1 = bxp[5], bx2 = bxp[6], by2 = bxp[7];
  float areaA = (ax2 - ax1) * (ay2 - ay1);
  float areaB = (bx2 - bx1) * (by2 - by1);

  float bestA = -1.0f, bestB = -1.0f;
  int idxA = P, idxB = P;
#pragma unroll 4
  for (int p = lane; p < P; p += 64) {
    float4 pr = ((const float4*)priors)[p];
    float pw2 = pr.z * 0.5f, ph2 = pr.w * 0.5f;
    float px1 = pr.x - pw2, py1 = pr.y - ph2;
    float px2 = pr.x + pw2, py2 = pr.y + ph2;
    float areaP = pr.z * pr.w;
    // object A
    {
      float iw = fminf(ax2, px2) - fmaxf(ax1, px1);
      float ih = fminf(ay2, py2) - fmaxf(ay1, py1);
      iw = fmaxf(iw, 0.0f);
      ih = fmaxf(ih, 0.0f);
      float inter = iw * ih;
      float iou = inter / (areaA + areaP - inter);
      if (iou > bestA) { bestA = iou; idxA = p; }  // strict > keeps smallest p
    }
    // object B
    {
      float iw = fminf(bx2, px2) - fmaxf(bx1, px1);
      float ih = fminf(by2, py2) - fmaxf(by1, py1);
      iw = fmaxf(iw, 0.0f);
      ih = fmaxf(ih, 0.0f);
      float inter = iw * ih;
      float iou = inter / (areaB + areaP - inter);
      if (iou > bestB) { bestB = iou; idxB = p; }
    }
  }
  for (int off = 32; off >= 1; off >>= 1) {
    float ov = __shfl_xor(bestA, off, 64);
    int oi = __shfl_xor(idxA, off, 64);
    if (ov > bestA || (ov == bestA && oi < idxA)) { bestA = ov; idxA = oi; }
    float ov2 = __shfl_xor(bestB, off, 64);
    int oi2 = __shfl_xor(idxB, off, 64);
    if (ov2 > bestB || (ov2 == bestB && oi2 < idxB)) { bestB = ov2; idxB = oi2; }
  }
  if (lane == 0) {
    objidx[b * M + obase] = idxA;
    objidx[b * M + obase + 1] = idxB;
  }
}

// ---------------- k2: per-prior match + loc partial + CE --------------------
// 4 consecutive priors/thread, float4 class reads, NO dynamic register-array
// indexing (cls extracted via predicated select -> no scratch spill).
__global__ __launch_bounds__(TPB2) void k2_perprior(
    const float* __restrict__ pred_loc, const float* __restrict__ pred_cls,
    const float* __restrict__ b_boxes, const int* __restrict__ b_labels,
    const float* __restrict__ priors, const int* __restrict__ objidx,
    float* __restrict__ ploc, float* __restrict__ pce, int* __restrict__ pnp,
    float* __restrict__ confneg) {
  int b = blockIdx.y;
  int p0 = blockIdx.x * PPB;
  int tid = threadIdx.x;

  __shared__ float sx1[M], sy1[M], sx2[M], sy2[M], sarea[M];
  __shared__ int slab[M], sobj[M];
  if (tid < M) {
    int m = tid;
    float4 bx = ((const float4*)b_boxes)[b * M + m];
    sx1[m] = bx.x; sy1[m] = bx.y; sx2[m] = bx.z; sy2[m] = bx.w;
    sarea[m] = (bx.z - bx.x) * (bx.w - bx.y);
    slab[m] = b_labels[b * M + m];
    sobj[m] = objidx[b * M + m];
  }
  __syncthreads();

  float locpart = 0.0f, cepospart = 0.0f;
  int npos = 0;
  int pbase = p0 + tid * PPT;
  if (pbase < P) {
    float4 pr[PPT], pl[PPT];
    const float4* prp = (const float4*)priors + pbase;
    const float4* plp = (const float4*)pred_loc + (size_t)b * P + pbase;
#pragma unroll
    for (int j = 0; j < PPT; j++) { pr[j] = prp[j]; pl[j] = plp[j]; }

    float px1[PPT], py1[PPT], px2[PPT], py2[PPT], areaP[PPT], best[PPT];
    int bm[PPT];
#pragma unroll
    for (int j = 0; j < PPT; j++) {
      float pw2 = pr[j].z * 0.5f, ph2 = pr[j].w * 0.5f;
      px1[j] = pr[j].x - pw2; py1[j] = pr[j].y - ph2;
      px2[j] = pr[j].x + pw2; py2[j] = pr[j].y + ph2;
      areaP[j] = pr[j].z * pr[j].w;
      best[j] = -1.0f; bm[j] = 0;
    }
    for (int m = 0; m < M; m++) {
      float bx1 = sx1[m], by1 = sy1[m], bx2 = sx2[m], by2 = sy2[m];
      float ar = sarea[m];
      int so = sobj[m];
#pragma unroll
      for (int j = 0; j < PPT; j++) {
        float iw = fminf(bx2, px2[j]) - fmaxf(bx1, px1[j]);
        float ih = fminf(by2, py2[j]) - fmaxf(by1, py1[j]);
        iw = fmaxf(iw, 0.0f);
        ih = fmaxf(ih, 0.0f);
        float inter = iw * ih;
        float iou = inter / (ar + areaP[j] - inter);
        if (so == pbase + j) iou = 1.0f;             // forced best prior
        if (iou > best[j]) { best[j] = iou; bm[j] = m; }  // first max
      }
    }

    // per-thread class base: float offset 84*tid within block slab (16B aligned)
    const float4* pc4t =
        (const float4*)(pred_cls + ((size_t)b * P + p0) * C) + 21 * tid;
    float4 cn;
    float* cnp = (float*)&cn;
#pragma unroll
    for (int j = 0; j < PPT; j++) {
      bool pos = best[j] >= 0.5f;
      int mj = bm[j];
      int cls = pos ? slab[mj] : 0;
      float bx1 = sx1[mj], by1 = sy1[mj], bx2 = sx2[mj], by2 = sy2[mj];
      float cx = (bx1 + bx2) * 0.5f, cy = (by1 + by2) * 0.5f;
      float w = bx2 - bx1, h = by2 - by1;
      float g0 = (cx - pr[j].x) * 10.0f / pr[j].z;
      float g1 = (cy - pr[j].y) * 10.0f / pr[j].w;
      float g2 = __logf(w / pr[j].z) * 5.0f;
      float g3 = __logf(h / pr[j].w) * 5.0f;
      if (pos) {
        locpart += fabsf(pl[j].x - g0) + fabsf(pl[j].y - g1) +
                   fabsf(pl[j].z - g2) + fabsf(pl[j].w - g3);
        npos++;
      }
      // prior j's 21 classes: thread-local floats 21j..21j+20 ->
      // float4s [5j..5j+5], in-window offset j. ALL indices below are
      // compile-time constants after unroll (no scratch).
      float4 u4[6];
#pragma unroll
      for (int q = 0; q < 6; q++) u4[q] = pc4t[5 * j + q];
      const float* u = (const float*)u4;
      float mx = u[j];
#pragma unroll
      for (int c = 1; c < C; c++) mx = fmaxf(mx, u[j + c]);
      float se = 0.0f;
      float vc = u[j];  // class 0 default
#pragma unroll
      for (int c = 0; c < C; c++) {
        float x = u[j + c];
        se += __expf(x - mx);
        if (c == cls) vc = x;  // predicated select, constant index
      }
      float ce = mx + __logf(se) - vc;
      cnp[j] = pos ? 0.0f : ce;
      cepospart += pos ? ce : 0.0f;
    }
    ((float4*)confneg)[((size_t)b * P + pbase) >> 2] = cn;
  }

  for (int off = 32; off >= 1; off >>= 1) {
    locpart += __shfl_down(locpart, off, 64);
    cepospart += __shfl_down(cepospart, off, 64);
    npos += __shfl_down(npos, off, 64);
  }
  __shared__ float rloc[4], rce[4];
  __shared__ int rnp[4];
  int wid = tid >> 6;
  if ((tid & 63) == 0) { rloc[wid] = locpart; rce[wid] = cepospart; rnp[wid] = npos; }
  __syncthreads();
  if (tid == 0) {
    int f = b * NB2 + blockIdx.x;
    ploc[f] = rloc[0] + rloc[1] + rloc[2] + rloc[3];
    pce[f] = rce[0] + rce[1] + rce[2] + rce[3];
    pnp[f] = rnp[0] + rnp[1] + rnp[2] + rnp[3];
  }
}

// ---------------- k3: per-image exact top-K + parallel finalize -------------
__global__ __launch_bounds__(1024) void k3_hardneg(
    const float* __restrict__ confneg,
    const float* __restrict__ ploc, const float* __restrict__ pce,
    const int* __restrict__ pnp,
    float* __restrict__ imgres, int* __restrict__ done,
    float* __restrict__ out) {
  int b = blockIdx.x;
  int tid = threadIdx.x;
  int wid = tid >> 6;
  int lane = tid & 63;

  __shared__ float s[P];                 // 34928 B
  __shared__ int histw[16 * 256];        // per-wave histograms
  __shared__ __align__(16) int cnt[256];
  __shared__ int sdig, scum, sK, sLast;
  __shared__ float sLoc, sCe, sNp;
  __shared__ float rsum[16], rl[16], rc[16], rh[16], rn[16];
  __shared__ int rcnt[16];

  const float* row = confneg + (size_t)b * P;
  for (int i = tid; i < P; i += 1024) s[i] = row[i];

  if (wid == 0) {  // wave 0: reduce this image's 9 per-block partials
    float lp = 0.0f, cp = 0.0f;
    int np = 0;
    if (lane < NB2) {
      int f = b * NB2 + lane;
      lp = ploc[f]; cp = pce[f]; np = pnp[f];
    }
    for (int off = 32; off >= 1; off >>= 1) {
      lp += __shfl_down(lp, off, 64);
      cp += __shfl_down(cp, off, 64);
      np += __shfl_down(np, off, 64);
    }
    if (lane == 0) {
      int K = np * 3;
      if (K > P) K = P;
      sK = K; sLoc = lp; sCe = cp; sNp = (float)np;
    }
  }
  __syncthreads();

  int K = sK;
  unsigned pfx = 0;
  int Krem = K;
#pragma unroll
  for (int pass = 3; pass >= 0; --pass) {
    int sh = pass * 8;
    for (int i = tid; i < 16 * 256; i += 1024) histw[i] = 0;
    __syncthreads();
    unsigned himask = (pass == 3) ? 0u : (0xFFFFFFFFu << (sh + 8));
    int* myh = &histw[wid * 256];
    for (int i = tid; i < P; i += 1024) {
      unsigned ub = __float_as_uint(s[i]);
      if ((ub & himask) == pfx) atomicAdd(&myh[(ub >> sh) & 255], 1);
    }
    __syncthreads();
    if (tid < 256) {
      int c = 0;
#pragma unroll
      for (int w = 0; w < 16; w++) c += histw[w * 256 + tid];
      cnt[tid] = c;
    }
    __syncthreads();
    if (wid == 0) {  // digit selection via wave suffix-scan
      int4 c4 = ((const int4*)cnt)[lane];
      int s3 = c4.w;
      int s2 = c4.z + s3;
      int s1 = c4.y + s2;
      int s0 = c4.x + s1;
      int suf = s0;
      for (int off = 1; off < 64; off <<= 1) {
        int t = __shfl_down(suf, off, 64);
        if (lane + off < 64) suf += t;
      }
      int above = suf - s0;
      int S0 = above + s0, S1 = above + s1, S2 = above + s2, S3 = above + s3;
      int S4 = above;
      if (S3 >= Krem && S4 < Krem) { sdig = 4 * lane + 3; scum = S4; }
      else if (S2 >= Krem && S3 < Krem) { sdig = 4 * lane + 2; scum = S3; }
      else if (S1 >= Krem && S2 < Krem) { sdig = 4 * lane + 1; scum = S2; }
      else if (S0 >= Krem && S1 < Krem) { sdig = 4 * lane + 0; scum = S1; }
    }
    __syncthreads();
    pfx |= ((unsigned)sdig) << sh;
    Krem -= scum;
  }
  float tau = __uint_as_float(pfx);  // exact K-th largest value

  float sum = 0.0f;
  int cgt = 0;
  for (int i = tid; i < P; i += 1024) {
    float v = s[i];
    if (v > tau) { sum += v; cgt++; }
  }
  for (int off = 32; off >= 1; off >>= 1) {
    sum += __shfl_down(sum, off, 64);
    cgt += __shfl_down(cgt, off, 64);
  }
  if (lane == 0) { rsum[wid] = sum; rcnt[wid] = cgt; }
  __syncthreads();
  if (tid == 0) {
    float stot = 0.0f;
    int ctot = 0;
#pragma unroll
    for (int w = 0; w < 16; w++) { stot += rsum[w]; ctot += rcnt[w]; }
    float hard = stot + (float)(K - ctot) * tau;  // exact tie handling
    imgres[b * 4 + 0] = sLoc;
    imgres[b * 4 + 1] = sCe;
    imgres[b * 4 + 2] = hard;
    imgres[b * 4 + 3] = sNp;
    __threadfence();
    int prev = atomicAdd(done, 1);
    sLast = (prev == B - 1) ? 1 : 0;
  }
  __syncthreads();
  if (sLast) {  // last block: parallel finalize (one image per thread)
    __threadfence();
    float l = 0.0f, c = 0.0f, h = 0.0f, n = 0.0f;
    if (tid < B) {
      l = atomicAdd(&imgres[tid * 4 + 0], 0.0f);
      c = atomicAdd(&imgres[tid * 4 + 1], 0.0f);
      h = atomicAdd(&imgres[tid * 4 + 2], 0.0f);
      n = atomicAdd(&imgres[tid * 4 + 3], 0.0f);
    }
    for (int off = 32; off >= 1; off >>= 1) {
      l += __shfl_down(l, off, 64);
      c += __shfl_down(c, off, 64);
      h += __shfl_down(h, off, 64);
      n += __shfl_down(n, off, 64);
    }
    if (lane == 0) { rl[wid] = l; rc[wid] = c; rh[wid] = h; rn[wid] = n; }
    __syncthreads();
    if (tid == 0) {
      float L = 0, Cc = 0, H = 0, N = 0;
#pragma unroll
      for (int w = 0; w < 16; w++) { L += rl[w]; Cc += rc[w]; H += rh[w]; N += rn[w]; }
      float loc = ALPHA * L / (N * 4.0f);
      float conf = (H + Cc) / N;
      out[0] = conf + loc;
      out[1] = loc;
      out[2] = conf;
    }
  }
}

extern "C" void kernel_launch(void* const* d_in, const int* in_sizes, int n_in,
                              void* d_out, int out_size, void* d_ws, size_t ws_size,
                              hipStream_t stream) {
  (void)in_sizes; (void)n_in; (void)out_size; (void)ws_size;
  const float* pred_loc = (const float*)d_in[0];
  const float* pred_cls = (const float*)d_in[1];
  const float* b_boxes = (const float*)d_in[2];
  const int* b_labels = (const int*)d_in[3];
  const float* priors = (const float*)d_in[4];
  float* out = (float*)d_out;

  // ws layout (4B units):
  // [0] done | [8..) ploc[B*NB2] | pce[B*NB2] | pnp[B*NB2] | imgres[B*4]
  // | objidx[B*M] | confneg[B*P]
  int* done = (int*)d_ws;
  float* ploc = (float*)d_ws + 8;
  float* pce = ploc + B * NB2;
  int* pnp = (int*)(pce + B * NB2);
  float* imgres = (float*)(pnp + B * NB2);
  int* objidx = (int*)(imgres + B * 4);
  float* confneg = (float*)(objidx + B * M);

  k1_objargmax<<<B * 4, 256, 0, stream>>>(b_boxes, priors, objidx, done);
  dim3 g2(NB2, B);
  k2_perprior<<<g2, TPB2, 0, stream>>>(pred_loc, pred_cls, b_boxes, b_labels,
                                       priors, objidx, ploc, pce, pnp, confneg);
  k3_hardneg<<<B, 1024, 0, stream>>>(confneg, ploc, pce, pnp, imgres, done, out);
}